// Round 7
// baseline (251.223 us; speedup 1.0000x reference)
//
#include <hip/hip_runtime.h>

// MCANet: out = x * sigmoid(w1d[c, center] * mean_{h,w}(x[b,c,h,w]))
// x: (16, 512, 64, 64) f32; w1d: (512, 5) f32; center tap = 2.
//
// r6 post-mortem: four different single-kernel schedules (coupled, barrier-
// free, pinned, 3-buffer software-pipelined) ALL land at 65-67 us => the
// ~4.1 TB/s cap is not scheduling; it is the mixed HBM read+write regime.
// Only single-personality streams measure fast on this chip: write-only
// fill = 6.7 TB/s, copy = 6.29. And x (134 MB) fits in the 256 MB
// Infinity Cache (r3's FETCH=65.6MB proved MALL retains x even across
// harness fills).
//
// So: split into a READ phase and a WRITE phase with MALL as the buffer.
//   K1: per-plane mean -> sigmoid gate into d_ws. PLAIN loads (allocate
//       x into L2/MALL). Pure-read 134 MB stream.
//   K2: out = x * gate. Copy-shaped, gate uniform per wave. PLAIN loads
//       (hit MALL: K1 touched all of x, nothing evicts between K1 and
//       K2) + NT stores (write-once; no L2 churn, no MALL eviction of x).
//       HBM sees ~only the 134 MB write stream.
// Discriminator: K2 FETCH_SIZE << 131072 KB iff the L3-residency bet holds.

#define NC 512
#define HW 4096            // 64*64
#define PER_LANE 16        // (HW/4) vf4s / 64 lanes

typedef float vf4 __attribute__((ext_vector_type(4)));

// ---------------- K1: read-only mean+gate ----------------
__global__ __launch_bounds__(256) void mcanet_mean_kernel(
    const float* __restrict__ x,
    const float* __restrict__ w1d,
    float* __restrict__ gates)
{
    const int lane  = threadIdx.x & 63;
    const int plane = (blockIdx.x << 2) + (threadIdx.x >> 6);  // b*NC + c

    const vf4* __restrict__ xin = (const vf4*)(x + (long long)plane * HW);

    // 16 independent plain vf4 loads (1 KB each, coalesced); accumulate.
    vf4 acc = xin[lane];
    #pragma unroll
    for (int i = 1; i < PER_LANE; ++i)
        acc += xin[lane + (i << 6)];
    float s = (acc.x + acc.y) + (acc.z + acc.w);

    #pragma unroll
    for (int off = 32; off > 0; off >>= 1)
        s += __shfl_xor(s, off, 64);

    if (lane == 0) {
        const float wc = w1d[(plane & (NC - 1)) * 5 + 2];
        const float zc = wc * (s * (1.0f / (float)HW));
        gates[plane] = 1.0f / (1.0f + __expf(-zc));
    }
}

// ---------------- K2: copy-shaped scale ----------------
// Each wave owns half a plane (2048 floats = 512 vf4s): gate index is
// uniform per wave (one broadcast load from the 32 KB table).
__global__ __launch_bounds__(256) void mcanet_scale_kernel(
    const float* __restrict__ x,
    const float* __restrict__ gates,
    float* __restrict__ out)
{
    const int lane = threadIdx.x & 63;
    const int wave = (blockIdx.x << 2) + (threadIdx.x >> 6);   // 0..16383

    const float g = gates[wave >> 1];

    const long long base = (long long)wave * (HW / 2);
    const vf4* __restrict__ xin = (const vf4*)(x + base);
    vf4* __restrict__ o = (vf4*)(out + base);

    // 8 independent {plain load -> mul -> NT store} per lane; loads do not
    // depend on g, so they all issue up front; stores trickle out like a copy.
    #pragma unroll
    for (int i = 0; i < 8; ++i) {
        vf4 r = xin[lane + (i << 6)] * g;
        __builtin_nontemporal_store(r, o + lane + (i << 6));
    }
}

extern "C" void kernel_launch(void* const* d_in, const int* in_sizes, int n_in,
                              void* d_out, int out_size, void* d_ws, size_t ws_size,
                              hipStream_t stream) {
    const float* x   = (const float*)d_in[0];  // (16,512,64,64)
    // d_in[1] = w1x1 (unused), d_in[2] = b1x1 (unused)
    const float* w1d = (const float*)d_in[3];  // (512,5)
    float* out   = (float*)d_out;
    float* gates = (float*)d_ws;               // 8192 floats = 32 KB

    const int planes = 16 * NC;                            // 8192
    mcanet_mean_kernel<<<planes / 4, 256, 0, stream>>>(x, w1d, gates);
    mcanet_scale_kernel<<<planes / 2, 256, 0, stream>>>(x, gates, out);
}

// Round 8
// 226.588 us; speedup vs baseline: 1.1087x; 1.1087x over previous
//
#include <hip/hip_runtime.h>

// MCANet: out = x * sigmoid(w1d[c, center] * mean_{h,w}(x[b,c,h,w]))
// x: (16, 512, 64, 64) f32; w1d: (512, 5) f32; center tap = 2.
//
// Final cache-policy quadrant (r7 post-mortem). Measured, single-kernel,
// 268 MB minimal traffic in all cases:
//   NT load + NT store     : 65 us   (r0/r2/r4/r6 — all schedules identical)
//   plain load + NT store  : 83 us   (r5)
//   plain load + plain st  : 80 us   (r3, HBM-side collapsed to 2.5 TB/s)
//   NT load + plain store  : THIS KERNEL
// Rationale: the 6.7 TB/s fill (fastest stream in this harness) uses PLAIN
// stores through L2 writeback; every 65-us variant used NT stores that
// bypass L2 write-combining. Plain LOADS are the proven poison arm (both
// plain-load rows slowest: read-allocation churn), so reads stay NT.
//
// Structure: one wave per plane, barrier-free (r2). 16 outstanding vf4
// loads/lane, packed accumulate, __shfl_xor butterfly (all 64 lanes end
// with the plane sum), per-lane sigmoid, immediate plain stores.

#define NC 512
#define HW 4096           // 64*64
#define PER_LANE 16       // (HW/4) vf4s / 64 lanes

typedef float vf4 __attribute__((ext_vector_type(4)));

__global__ __launch_bounds__(256) void mcanet_gate_kernel(
    const float* __restrict__ x,
    const float* __restrict__ w1d,
    float* __restrict__ out)
{
    const int wave  = threadIdx.x >> 6;
    const int lane  = threadIdx.x & 63;
    const int plane = (blockIdx.x << 2) + wave;   // b*NC + c
    const int c = plane & (NC - 1);

    // Tiny gate-weight load first: 10 KB table, cache-resident; its
    // latency hides under the 16 plane loads.
    const float wc = w1d[c * 5 + 2];

    const long long base = (long long)plane * HW;
    const vf4* __restrict__ xin = (const vf4*)(x + base);
    vf4* __restrict__ o = (vf4*)(out + base);

    // Wave covers its 16 KB plane: lane i reads vf4 (lane + 64*k),
    // i.e. 1 KB contiguous per load instruction, 16 in flight.
    vf4 v[PER_LANE];
    #pragma unroll
    for (int i = 0; i < PER_LANE; ++i)
        v[i] = __builtin_nontemporal_load(xin + lane + (i << 6));

    // Packed accumulate (v_pk_add_f32), then horizontal.
    vf4 acc = v[0];
    #pragma unroll
    for (int i = 1; i < PER_LANE; ++i)
        acc += v[i];
    float s = (acc.x + acc.y) + (acc.z + acc.w);

    // Butterfly: every lane ends with the full plane sum.
    #pragma unroll
    for (int off = 32; off > 0; off >>= 1)
        s += __shfl_xor(s, off, 64);

    const float zc = wc * (s * (1.0f / (float)HW));
    const float g  = 1.0f / (1.0f + __expf(-zc));

    // PLAIN stores: route the write stream through L2 writeback (the
    // 6.7 TB/s fill path), instead of the NT bypass.
    #pragma unroll
    for (int i = 0; i < PER_LANE; ++i) {
        vf4 r = v[i] * g;
        o[lane + (i << 6)] = r;
    }
}

extern "C" void kernel_launch(void* const* d_in, const int* in_sizes, int n_in,
                              void* d_out, int out_size, void* d_ws, size_t ws_size,
                              hipStream_t stream) {
    const float* x   = (const float*)d_in[0];  // (16,512,64,64)
    // d_in[1] = w1x1 (unused), d_in[2] = b1x1 (unused)
    const float* w1d = (const float*)d_in[3];  // (512,5)
    float* out = (float*)d_out;

    const int planes = 16 * NC;                // 8192 planes
    mcanet_gate_kernel<<<planes / 4, 256, 0, stream>>>(x, w1d, out);
}